// Round 1
// baseline (220.252 us; speedup 1.0000x reference)
//
#include <hip/hip_runtime.h>

#define LN_EPS 1e-5f

// One block per graph (512 blocks, 256 threads). Entire net fused.
// LDS budget: 40000 + 8000 + 8000 + 6400 + ~2.3KB = ~63.6 KB -> 2 blocks/CU.
__global__ __launch_bounds__(256) void fused_net(
    const float* __restrict__ feat, const int* __restrict__ edge_src,
    const float* __restrict__ self_feat, const float* __restrict__ x3d,
    const float* __restrict__ W1, const float* __restrict__ b1,
    const float* __restrict__ W2, const float* __restrict__ b2,
    const float* __restrict__ Wv2, const float* __restrict__ Wo2,
    const float* __restrict__ g2, const float* __restrict__ be2,
    const float* __restrict__ Wv3, const float* __restrict__ Wo3,
    const float* __restrict__ g3, const float* __restrict__ be3,
    const float* __restrict__ Wf1, const float* __restrict__ bf1,
    const float* __restrict__ Wf2, const float* __restrict__ bf2,
    float* __restrict__ out)
{
    __shared__ __align__(16) float sF[10000];  // feat -> agg1 -> h1 -> h2(first 2000)
    __shared__ __align__(16) float sT[2000];   // t2 = h1 @ W2^T
    __shared__ __align__(16) float sW[2000];   // W-tile staging (W1t chunks, then W2t)
    __shared__ int   sSrc[1600];
    __shared__ float sSF[200];
    __shared__ float sX3[100];
    __shared__ float sV[32];
    __shared__ float sY[20];
    __shared__ float sHg[20];
    __shared__ float sP[200];
    __shared__ float sO[10];

    const int g   = blockIdx.x;
    const int tid = threadIdx.x;
    const int tn  = tid >> 5;   // 0..7
    const int tj  = tid & 31;   // column (j4 for GEMM1, j for GEMM2)

    // ---------- phase 0: stage feat block, edge srcs, per-graph vectors ----------
    {
        const float* fg = feat + g * 10000;
        for (int i = tid; i < 10000; i += 256) sF[i] = fg[i];
        const int* es = edge_src + g * 1600;
        const int base = g * 100;
        for (int i = tid; i < 1600; i += 256) sSrc[i] = es[i] - base;
        for (int i = tid; i < 200; i += 256) sSF[i] = self_feat[g * 200 + i];
        if (tid < 100) sX3[tid] = x3d[g * 100 + tid];
    }
    __syncthreads();

    // ---------- phase 1: agg1[n][k] = mean_e feat[src][k], into registers ----------
    float4 r[10];
    for (int it = 0; it < 10; ++it) {
        const int idx = tid + it * 256;           // (n, k4): n=idx/25, k4=idx%25
        if (idx < 2500) {
            const int n = idx / 25, kq = idx % 25;
            const int* s = &sSrc[n * 16];
            float4 acc = make_float4(0.f, 0.f, 0.f, 0.f);
            #pragma unroll
            for (int e = 0; e < 16; ++e) {
                const float4 v = *(const float4*)&sF[s[e] * 100 + kq * 4];
                acc.x += v.x; acc.y += v.y; acc.z += v.z; acc.w += v.w;
            }
            const float inv = 1.f / 16.f;
            acc.x *= inv; acc.y *= inv; acc.z *= inv; acc.w *= inv;
            r[it] = acc;
        }
    }
    __syncthreads();
    for (int it = 0; it < 10; ++it) {
        const int idx = tid + it * 256;
        if (idx < 2500) *(float4*)&sF[idx * 4] = r[it];  // idx*4 == n*100 + k4*4
    }
    __syncthreads();

    // ---------- phase 2: h1 = relu(agg1 @ W1^T + b1), k chunked 5x20 ----------
    float4 acc1[13];
    #pragma unroll
    for (int ni = 0; ni < 13; ++ni) acc1[ni] = make_float4(0.f, 0.f, 0.f, 0.f);

    for (int c = 0; c < 5; ++c) {
        // stage transposed chunk: sW[kk*100 + j] = W1[j][c*20+kk], kk in [0,20)
        for (int i = tid; i < 2000; i += 256) {
            const int j = i / 20, kk = i % 20;
            sW[kk * 100 + j] = W1[j * 100 + c * 20 + kk];
        }
        __syncthreads();
        if (tj < 25) {
            #pragma unroll
            for (int k4 = 0; k4 < 5; ++k4) {
                const float4 w0 = *(const float4*)&sW[(k4 * 4 + 0) * 100 + tj * 4];
                const float4 w1 = *(const float4*)&sW[(k4 * 4 + 1) * 100 + tj * 4];
                const float4 w2 = *(const float4*)&sW[(k4 * 4 + 2) * 100 + tj * 4];
                const float4 w3 = *(const float4*)&sW[(k4 * 4 + 3) * 100 + tj * 4];
                #pragma unroll
                for (int ni = 0; ni < 13; ++ni) {
                    const int n = tn + ni * 8;
                    if (n < 100) {
                        const float4 a = *(const float4*)&sF[n * 100 + c * 20 + k4 * 4];
                        float4 acc = acc1[ni];
                        acc.x += a.x * w0.x + a.y * w1.x + a.z * w2.x + a.w * w3.x;
                        acc.y += a.x * w0.y + a.y * w1.y + a.z * w2.y + a.w * w3.y;
                        acc.z += a.x * w0.z + a.y * w1.z + a.z * w2.z + a.w * w3.z;
                        acc.w += a.x * w0.w + a.y * w1.w + a.z * w2.w + a.w * w3.w;
                        acc1[ni] = acc;
                    }
                }
            }
        }
        __syncthreads();
    }
    if (tj < 25) {
        const float4 bb = *(const float4*)&b1[tj * 4];
        #pragma unroll
        for (int ni = 0; ni < 13; ++ni) {
            const int n = tn + ni * 8;
            if (n < 100) {
                float4 a = acc1[ni];
                a.x = fmaxf(a.x + bb.x, 0.f);
                a.y = fmaxf(a.y + bb.y, 0.f);
                a.z = fmaxf(a.z + bb.z, 0.f);
                a.w = fmaxf(a.w + bb.w, 0.f);
                *(float4*)&sF[n * 100 + tj * 4] = a;  // h1
            }
        }
    }
    __syncthreads();

    // ---------- phase 3: t2 = h1 @ W2^T  (no bias; bias after aggregation) ----------
    for (int i = tid; i < 2000; i += 256) {
        const int j = i / 100, k = i % 100;
        sW[k * 20 + j] = W2[i];                   // W2t
    }
    __syncthreads();
    if (tj < 20) {
        float acc2[13];
        #pragma unroll
        for (int ni = 0; ni < 13; ++ni) acc2[ni] = 0.f;
        for (int k4 = 0; k4 < 25; ++k4) {
            const float w0 = sW[(k4 * 4 + 0) * 20 + tj];
            const float w1 = sW[(k4 * 4 + 1) * 20 + tj];
            const float w2 = sW[(k4 * 4 + 2) * 20 + tj];
            const float w3 = sW[(k4 * 4 + 3) * 20 + tj];
            #pragma unroll
            for (int ni = 0; ni < 13; ++ni) {
                const int n = tn + ni * 8;
                if (n < 100) {
                    const float4 a = *(const float4*)&sF[n * 100 + k4 * 4];
                    acc2[ni] += a.x * w0 + a.y * w1 + a.z * w2 + a.w * w3;
                }
            }
        }
        #pragma unroll
        for (int ni = 0; ni < 13; ++ni) {
            const int n = tn + ni * 8;
            if (n < 100) sT[n * 20 + tj] = acc2[ni];
        }
    }
    __syncthreads();

    // ---------- phase 4: h2 = relu(mean_e t2[src] + b2) -> sF[0..2000) ----------
    for (int it = 0; it < 8; ++it) {
        const int idx = tid + it * 256;
        if (idx < 2000) {
            const int n = idx / 20, j = idx % 20;
            const int* s = &sSrc[n * 16];
            float a = 0.f;
            #pragma unroll
            for (int e = 0; e < 16; ++e) a += sT[s[e] * 20 + j];
            a = a * (1.f / 16.f) + b2[j];
            sF[idx] = fmaxf(a, 0.f);
        }
    }
    __syncthreads();

    // ---------- phase 5: hg[j] = mean_n h2[n][j] ----------
    if (tid < 200) {
        const int n0 = tid / 20, j = tid % 20;
        float p = 0.f;
        #pragma unroll
        for (int m = 0; m < 10; ++m) p += sF[(n0 * 10 + m) * 20 + j];
        sP[tid] = p;
    }
    __syncthreads();
    if (tid < 20) {
        float p = 0.f;
        #pragma unroll
        for (int i = 0; i < 10; ++i) p += sP[i * 20 + tid];
        sHg[tid] = p * 0.01f;
    }
    __syncthreads();

    // ---------- phase 6: cross-attn 2 (len-1 softmax == identity on V path) ----------
    if (tid < 32) {
        float v = 0.f;
        for (int c = 0; c < 200; ++c) v += Wv2[tid * 200 + c] * sSF[c];
        sV[tid] = v;
    }
    __syncthreads();
    if (tid < 20) {
        float z = 0.f;
        #pragma unroll
        for (int c = 0; c < 32; ++c) z += Wo2[tid * 32 + c] * sV[c];
        sY[tid] = sHg[tid] + z;
    }
    __syncthreads();
    if (tid < 20) {
        float mu = 0.f;
        #pragma unroll
        for (int i = 0; i < 20; ++i) mu += sY[i];
        mu *= 0.05f;
        float var = 0.f;
        #pragma unroll
        for (int i = 0; i < 20; ++i) { const float d = sY[i] - mu; var += d * d; }
        var *= 0.05f;
        const float inv = 1.f / sqrtf(var + LN_EPS);
        sHg[tid] = (sY[tid] - mu) * inv * g2[tid] + be2[tid];
    }
    __syncthreads();

    // ---------- phase 7: cross-attn 3 ----------
    if (tid < 32) {
        float v = 0.f;
        for (int c = 0; c < 100; ++c) v += Wv3[tid * 100 + c] * sX3[c];
        sV[tid] = v;
    }
    __syncthreads();
    if (tid < 20) {
        float z = 0.f;
        #pragma unroll
        for (int c = 0; c < 32; ++c) z += Wo3[tid * 32 + c] * sV[c];
        sY[tid] = sHg[tid] + z;
    }
    __syncthreads();
    if (tid < 20) {
        float mu = 0.f;
        #pragma unroll
        for (int i = 0; i < 20; ++i) mu += sY[i];
        mu *= 0.05f;
        float var = 0.f;
        #pragma unroll
        for (int i = 0; i < 20; ++i) { const float d = sY[i] - mu; var += d * d; }
        var *= 0.05f;
        const float inv = 1.f / sqrtf(var + LN_EPS);
        sHg[tid] = (sY[tid] - mu) * inv * g3[tid] + be3[tid];
    }
    __syncthreads();

    // ---------- phase 8: MLP head ----------
    if (tid < 10) {
        float a = bf1[tid];
        #pragma unroll
        for (int k = 0; k < 20; ++k) a += Wf1[tid * 20 + k] * sHg[k];
        sO[tid] = fmaxf(a, 0.f);
    }
    __syncthreads();
    if (tid == 0) {
        float a = bf2[0];
        #pragma unroll
        for (int i = 0; i < 10; ++i) a += Wf2[i] * sO[i];
        out[g] = a;
    }
}

extern "C" void kernel_launch(void* const* d_in, const int* in_sizes, int n_in,
                              void* d_out, int out_size, void* d_ws, size_t ws_size,
                              hipStream_t stream) {
    const float* feat      = (const float*)d_in[0];
    const int*   edge_src  = (const int*)  d_in[1];
    // d_in[2] = edge_dst (implied by layout: node n's edges at n*16..n*16+15)
    const float* self_feat = (const float*)d_in[3];
    const float* x3d       = (const float*)d_in[4];
    const float* W1  = (const float*)d_in[5];
    const float* b1  = (const float*)d_in[6];
    const float* W2  = (const float*)d_in[7];
    const float* b2  = (const float*)d_in[8];
    // d_in[9]=Wq2, d_in[10]=Wk2 unused (softmax over length-1 axis == 1)
    const float* Wv2 = (const float*)d_in[11];
    const float* Wo2 = (const float*)d_in[12];
    const float* g2  = (const float*)d_in[13];
    const float* be2 = (const float*)d_in[14];
    // d_in[15]=Wq3, d_in[16]=Wk3 unused
    const float* Wv3 = (const float*)d_in[17];
    const float* Wo3 = (const float*)d_in[18];
    const float* g3  = (const float*)d_in[19];
    const float* be3 = (const float*)d_in[20];
    const float* Wf1 = (const float*)d_in[21];
    const float* bf1 = (const float*)d_in[22];
    const float* Wf2 = (const float*)d_in[23];
    const float* bf2 = (const float*)d_in[24];

    fused_net<<<512, 256, 0, stream>>>(feat, edge_src, self_feat, x3d,
                                       W1, b1, W2, b2,
                                       Wv2, Wo2, g2, be2,
                                       Wv3, Wo3, g3, be3,
                                       Wf1, bf1, Wf2, bf2,
                                       (float*)d_out);
}

// Round 2
// 171.156 us; speedup vs baseline: 1.2869x; 1.2869x over previous
//
#include <hip/hip_runtime.h>

#define LN_EPS 1e-5f

typedef __attribute__((ext_vector_type(8))) short bf16x8;
typedef __attribute__((ext_vector_type(4))) float f32x4;

// LDS arena layout (ushort indices). Row stride S=136 bf16 (272 B = 17*16B:
// 16B-aligned rows, bank offset 68 dw == 4 mod 32 -> 2-way conflicts only, free).
#define S 136
#define OFF_F 0        // feat -> T1t -> h1            (100 rows)
#define OFF_W 13600    // W1p  -> A (dense agg matrix) (100 rows)
#define OFF_S 27200    // W2p  -> T2t                  (20 rows + zero spill)
#define FLT_OFF 29920  // float scratch region
#define ARENA_U 31552  // 63104 B total

// float-region offsets
#define FSF 0    // self_feat [200]
#define FX3 200  // x3d [100]
#define FV2 300  // V2 [32]
#define FV3 332  // V3 [32]
#define FZ2 364  // Z2 [20]
#define FZ3 384  // Z3 [20]
#define FHG 404  // hg accumulator [20]
#define FY  424  // LN scratch [20]
#define FYB 444  // LN scratch [20]
#define FO  464  // MLP hidden [10]

__device__ __forceinline__ unsigned short bf16rne(float x) {
    union { float f; unsigned u; } v; v.f = x;
    unsigned r = (v.u + 0x7FFFu + ((v.u >> 16) & 1u)) >> 16;
    return (unsigned short)r;
}

// One K=128 pass over NT n-tiles for up to two m-tile rows (mr1<0 -> skip).
// A stored row-major [m][k]; B stored as Bt[n][k] (k contiguous). Both padded
// with zeros in k in [100,128).
template<int NT>
__device__ __forceinline__ void gemm_tiles(const unsigned short* __restrict__ ar,
    int Abase, int Bbase, int mr0, int mr1, int lm, int lq,
    f32x4 (&acc0)[NT], f32x4 (&acc1)[NT])
{
    #pragma unroll
    for (int ks = 0; ks < 4; ++ks) {
        const int k = ks * 32 + lq * 8;
        bf16x8 a0 = *(const bf16x8*)&ar[Abase + (mr0 * 16 + lm) * S + k];
        bf16x8 a1 = a0;
        if (mr1 >= 0) a1 = *(const bf16x8*)&ar[Abase + (mr1 * 16 + lm) * S + k];
        #pragma unroll
        for (int n = 0; n < NT; ++n) {
            bf16x8 b = *(const bf16x8*)&ar[Bbase + (n * 16 + lm) * S + k];
            acc0[n] = __builtin_amdgcn_mfma_f32_16x16x32_bf16(a0, b, acc0[n], 0, 0, 0);
            if (mr1 >= 0)
                acc1[n] = __builtin_amdgcn_mfma_f32_16x16x32_bf16(a1, b, acc1[n], 0, 0, 0);
        }
    }
}

__global__ __launch_bounds__(256) void fused_net_mfma(
    const float* __restrict__ feat, const int* __restrict__ edge_src,
    const float* __restrict__ self_feat, const float* __restrict__ x3d,
    const float* __restrict__ W1, const float* __restrict__ b1,
    const float* __restrict__ W2, const float* __restrict__ b2,
    const float* __restrict__ Wv2, const float* __restrict__ Wo2,
    const float* __restrict__ g2, const float* __restrict__ be2,
    const float* __restrict__ Wv3, const float* __restrict__ Wo3,
    const float* __restrict__ g3, const float* __restrict__ be3,
    const float* __restrict__ Wf1, const float* __restrict__ bf1,
    const float* __restrict__ Wf2, const float* __restrict__ bf2,
    float* __restrict__ out)
{
    __shared__ __align__(16) unsigned short ar[ARENA_U];
    float* fl = (float*)&ar[FLT_OFF];

    const int g    = blockIdx.x;
    const int tid  = threadIdx.x;
    const int w    = tid >> 6;
    const int lane = tid & 63;
    const int lm   = lane & 15;
    const int lq   = lane >> 4;
    const int mr0  = w;
    const int mr1  = (w + 4 < 7) ? (w + 4) : -1;

    // ---- phase 0: zero the whole arena (pads must be exactly 0) ----
    {
        const uint4 z = make_uint4(0u, 0u, 0u, 0u);
        for (int i = tid; i < ARENA_U / 8; i += 256)
            *(uint4*)&ar[i * 8] = z;
    }
    __syncthreads();

    // ---- phase 1: stage feat, W1, W2 (bf16, padded) + self_feat, x3d (f32) ----
    {
        const float* fg = feat + g * 10000;
        for (int i = tid; i < 2500; i += 256) {
            const int n = i / 25, k4 = (i % 25) * 4;
            const float4 v = *(const float4*)&fg[n * 100 + k4];
            *(ushort4*)&ar[OFF_F + n * S + k4] =
                make_ushort4(bf16rne(v.x), bf16rne(v.y), bf16rne(v.z), bf16rne(v.w));
        }
        for (int i = tid; i < 2500; i += 256) {
            const int n = i / 25, k4 = (i % 25) * 4;
            const float4 v = *(const float4*)&W1[n * 100 + k4];
            *(ushort4*)&ar[OFF_W + n * S + k4] =
                make_ushort4(bf16rne(v.x), bf16rne(v.y), bf16rne(v.z), bf16rne(v.w));
        }
        for (int i = tid; i < 500; i += 256) {
            const int n = i / 25, k4 = (i % 25) * 4;
            const float4 v = *(const float4*)&W2[n * 100 + k4];
            *(ushort4*)&ar[OFF_S + n * S + k4] =
                make_ushort4(bf16rne(v.x), bf16rne(v.y), bf16rne(v.z), bf16rne(v.w));
        }
        for (int i = tid; i < 200; i += 256) fl[FSF + i] = self_feat[g * 200 + i];
        if (tid < 100) fl[FX3 + tid] = x3d[g * 100 + tid];
    }
    __syncthreads();

    // ---- phase 2: GEMM1  T1 = feat @ W1^T ; wave 0 also does the V-dots ----
    f32x4 acc0[7], acc1[7];
    {
        const f32x4 z4 = {0.f, 0.f, 0.f, 0.f};
        #pragma unroll
        for (int n = 0; n < 7; ++n) { acc0[n] = z4; acc1[n] = z4; }
    }
    if (w == 0) {
        if (lane < 32) {
            const float* wr = Wv2 + lane * 200;
            float s = 0.f;
            for (int c = 0; c < 50; ++c) {
                const float4 a = *(const float4*)&wr[c * 4];
                s += a.x * fl[FSF + c * 4] + a.y * fl[FSF + c * 4 + 1]
                   + a.z * fl[FSF + c * 4 + 2] + a.w * fl[FSF + c * 4 + 3];
            }
            fl[FV2 + lane] = s;
        } else {
            const int r = lane - 32;
            const float* wr = Wv3 + r * 100;
            float s = 0.f;
            for (int c = 0; c < 25; ++c) {
                const float4 a = *(const float4*)&wr[c * 4];
                s += a.x * fl[FX3 + c * 4] + a.y * fl[FX3 + c * 4 + 1]
                   + a.z * fl[FX3 + c * 4 + 2] + a.w * fl[FX3 + c * 4 + 3];
            }
            fl[FV3 + r] = s;
        }
    }
    gemm_tiles<7>(ar, OFF_F, OFF_W, mr0, mr1, lm, lq, acc0, acc1);
    __syncthreads();

    // ---- phase 3: write T1t (transposed, into bufF), zero bufW, Z2/Z3 ----
    {
        const uint4 z = make_uint4(0u, 0u, 0u, 0u);
        for (int i = tid; i < 13600 / 8; i += 256)
            *(uint4*)&ar[OFF_W + i * 8] = z;
    }
    {
        // C layout: col = n*16+lm (T1 feature), rows = mr*16+lq*4+r (node)
        #pragma unroll
        for (int n = 0; n < 7; ++n) {
            const int cc = n * 16 + lm, m0 = mr0 * 16 + lq * 4;
            if (cc < 100 && m0 <= 96) {
                const f32x4 v = acc0[n];
                *(ushort4*)&ar[OFF_F + cc * S + m0] =
                    make_ushort4(bf16rne(v[0]), bf16rne(v[1]), bf16rne(v[2]), bf16rne(v[3]));
            }
        }
        if (mr1 >= 0) {
            #pragma unroll
            for (int n = 0; n < 7; ++n) {
                const int cc = n * 16 + lm, m0 = mr1 * 16 + lq * 4;
                if (cc < 100 && m0 <= 96) {
                    const f32x4 v = acc1[n];
                    *(ushort4*)&ar[OFF_F + cc * S + m0] =
                        make_ushort4(bf16rne(v[0]), bf16rne(v[1]), bf16rne(v[2]), bf16rne(v[3]));
                }
            }
        }
    }
    if (tid >= 64 && tid < 84) {
        const int j = tid - 64; float s = 0.f;
        #pragma unroll
        for (int c = 0; c < 32; ++c) s += Wo2[j * 32 + c] * fl[FV2 + c];
        fl[FZ2 + j] = s;
    } else if (tid >= 96 && tid < 116) {
        const int j = tid - 96; float s = 0.f;
        #pragma unroll
        for (int c = 0; c < 32; ++c) s += Wo3[j * 32 + c] * fl[FV3 + c];
        fl[FZ3 + j] = s;
    }
    __syncthreads();

    // ---- phase 4: build dense aggregation matrix A[dst][src] = count/16 ----
    if (tid < 100) {
        const int* ep = edge_src + g * 1600 + tid * 16;
        int sr[16];
        {
            int4 e;
            e = *(const int4*)&ep[0];  sr[0]=e.x;  sr[1]=e.y;  sr[2]=e.z;  sr[3]=e.w;
            e = *(const int4*)&ep[4];  sr[4]=e.x;  sr[5]=e.y;  sr[6]=e.z;  sr[7]=e.w;
            e = *(const int4*)&ep[8];  sr[8]=e.x;  sr[9]=e.y;  sr[10]=e.z; sr[11]=e.w;
            e = *(const int4*)&ep[12]; sr[12]=e.x; sr[13]=e.y; sr[14]=e.z; sr[15]=e.w;
        }
        const int base = g * 100;
        #pragma unroll
        for (int i = 0; i < 16; ++i) sr[i] -= base;
        #pragma unroll
        for (int i = 0; i < 16; ++i) {
            int cnt = 0;
            #pragma unroll
            for (int j = 0; j < 16; ++j) cnt += (sr[j] == sr[i]);
            ar[OFF_W + tid * S + sr[i]] = bf16rne((float)cnt * 0.0625f);  // idempotent
        }
    }
    __syncthreads();

    // ---- phase 5: GEMM2  C2 = A @ T1 ----
    {
        const f32x4 z4 = {0.f, 0.f, 0.f, 0.f};
        #pragma unroll
        for (int n = 0; n < 7; ++n) { acc0[n] = z4; acc1[n] = z4; }
    }
    gemm_tiles<7>(ar, OFF_W, OFF_F, mr0, mr1, lm, lq, acc0, acc1);
    __syncthreads();

    // ---- phase 6: h1 = relu(C2 + b1) row-major into bufF ----
    {
        #pragma unroll
        for (int n = 0; n < 7; ++n) {
            const int cc = n * 16 + lm;
            if (cc < 100) {
                const float bb = b1[cc];
                #pragma unroll
                for (int r = 0; r < 4; ++r) {
                    const int m = mr0 * 16 + lq * 4 + r;
                    if (m < 100)
                        ar[OFF_F + m * S + cc] = bf16rne(fmaxf(acc0[n][r] + bb, 0.f));
                }
                if (mr1 >= 0) {
                    #pragma unroll
                    for (int r = 0; r < 4; ++r) {
                        const int m = mr1 * 16 + lq * 4 + r;
                        if (m < 100)
                            ar[OFF_F + m * S + cc] = bf16rne(fmaxf(acc1[n][r] + bb, 0.f));
                    }
                }
            }
        }
    }
    __syncthreads();

    // ---- phase 7: GEMM3  T2 = h1 @ W2^T  (N=20 -> 2 n-tiles) ----
    f32x4 sacc0[2], sacc1[2];
    {
        const f32x4 z4 = {0.f, 0.f, 0.f, 0.f};
        sacc0[0] = sacc0[1] = z4; sacc1[0] = sacc1[1] = z4;
    }
    gemm_tiles<2>(ar, OFF_F, OFF_S, mr0, mr1, lm, lq, sacc0, sacc1);
    __syncthreads();

    // ---- phase 8: write T2t (transposed) into OFF_S (over W2p) ----
    {
        #pragma unroll
        for (int n = 0; n < 2; ++n) {
            const int cc = n * 16 + lm, m0 = mr0 * 16 + lq * 4;
            if (cc < 20 && m0 <= 96) {
                const f32x4 v = sacc0[n];
                *(ushort4*)&ar[OFF_S + cc * S + m0] =
                    make_ushort4(bf16rne(v[0]), bf16rne(v[1]), bf16rne(v[2]), bf16rne(v[3]));
            }
        }
        if (mr1 >= 0) {
            #pragma unroll
            for (int n = 0; n < 2; ++n) {
                const int cc = n * 16 + lm, m0 = mr1 * 16 + lq * 4;
                if (cc < 20 && m0 <= 96) {
                    const f32x4 v = sacc1[n];
                    *(ushort4*)&ar[OFF_S + cc * S + m0] =
                        make_ushort4(bf16rne(v[0]), bf16rne(v[1]), bf16rne(v[2]), bf16rne(v[3]));
                }
            }
        }
    }
    __syncthreads();

    // ---- phase 9: GEMM4  C4 = A @ T2 ; fused relu(+b2) column-mean -> hg ----
    {
        const f32x4 z4 = {0.f, 0.f, 0.f, 0.f};
        sacc0[0] = sacc0[1] = z4; sacc1[0] = sacc1[1] = z4;
    }
    gemm_tiles<2>(ar, OFF_W, OFF_S, mr0, mr1, lm, lq, sacc0, sacc1);
    {
        #pragma unroll
        for (int n = 0; n < 2; ++n) {
            const int cc = n * 16 + lm;
            const float bb = (cc < 20) ? b2[cc] : 0.f;
            float s0 = 0.f;
            #pragma unroll
            for (int r = 0; r < 4; ++r) {
                const int m = mr0 * 16 + lq * 4 + r;
                if (m < 100) s0 += fmaxf(sacc0[n][r] + bb, 0.f);
            }
            if (mr1 >= 0) {
                #pragma unroll
                for (int r = 0; r < 4; ++r) {
                    const int m = mr1 * 16 + lq * 4 + r;
                    if (m < 100) s0 += fmaxf(sacc1[n][r] + bb, 0.f);
                }
            }
            s0 += __shfl_down(s0, 32);
            s0 += __shfl_down(s0, 16);
            if (lane < 16 && cc < 20) atomicAdd(&fl[FHG + cc], s0);
        }
    }
    __syncthreads();

    // ---- tail: attn residuals + LN x2 + MLP (tiny) ----
    if (tid < 20) fl[FY + tid] = fl[FHG + tid] * 0.01f + fl[FZ2 + tid];
    __syncthreads();
    if (tid < 20) {
        float mu = 0.f;
        #pragma unroll
        for (int i = 0; i < 20; ++i) mu += fl[FY + i];
        mu *= 0.05f;
        float var = 0.f;
        #pragma unroll
        for (int i = 0; i < 20; ++i) { const float d = fl[FY + i] - mu; var += d * d; }
        var *= 0.05f;
        const float inv = 1.f / sqrtf(var + LN_EPS);
        fl[FYB + tid] = (fl[FY + tid] - mu) * inv * g2[tid] + be2[tid] + fl[FZ3 + tid];
    }
    __syncthreads();
    if (tid < 20) {
        float mu = 0.f;
        #pragma unroll
        for (int i = 0; i < 20; ++i) mu += fl[FYB + i];
        mu *= 0.05f;
        float var = 0.f;
        #pragma unroll
        for (int i = 0; i < 20; ++i) { const float d = fl[FYB + i] - mu; var += d * d; }
        var *= 0.05f;
        const float inv = 1.f / sqrtf(var + LN_EPS);
        fl[FY + tid] = (fl[FYB + tid] - mu) * inv * g3[tid] + be3[tid];
    }
    __syncthreads();
    if (tid < 10) {
        float a = bf1[tid];
        #pragma unroll
        for (int k = 0; k < 20; ++k) a += Wf1[tid * 20 + k] * fl[FY + k];
        fl[FO + tid] = fmaxf(a, 0.f);
    }
    __syncthreads();
    if (tid == 0) {
        float a = bf2[0];
        #pragma unroll
        for (int i = 0; i < 10; ++i) a += fl[FO + i] * Wf2[i];
        out[g] = a;
    }
}

extern "C" void kernel_launch(void* const* d_in, const int* in_sizes, int n_in,
                              void* d_out, int out_size, void* d_ws, size_t ws_size,
                              hipStream_t stream) {
    const float* feat      = (const float*)d_in[0];
    const int*   edge_src  = (const int*)  d_in[1];
    // d_in[2] = edge_dst (implied by layout: node n's edges at n*16..n*16+15)
    const float* self_feat = (const float*)d_in[3];
    const float* x3d       = (const float*)d_in[4];
    const float* W1  = (const float*)d_in[5];
    const float* b1  = (const float*)d_in[6];
    const float* W2  = (const float*)d_in[7];
    const float* b2  = (const float*)d_in[8];
    // d_in[9]=Wq2, d_in[10]=Wk2 unused (softmax over length-1 axis == 1)
    const float* Wv2 = (const float*)d_in[11];
    const float* Wo2 = (const float*)d_in[12];
    const float* g2  = (const float*)d_in[13];
    const float* be2 = (const float*)d_in[14];
    // d_in[15]=Wq3, d_in[16]=Wk3 unused
    const float* Wv3 = (const float*)d_in[17];
    const float* Wo3 = (const float*)d_in[18];
    const float* g3  = (const float*)d_in[19];
    const float* be3 = (const float*)d_in[20];
    const float* Wf1 = (const float*)d_in[21];
    const float* bf1 = (const float*)d_in[22];
    const float* Wf2 = (const float*)d_in[23];
    const float* bf2 = (const float*)d_in[24];

    fused_net_mfma<<<512, 256, 0, stream>>>(feat, edge_src, self_feat, x3d,
                                            W1, b1, W2, b2,
                                            Wv2, Wo2, g2, be2,
                                            Wv3, Wo3, g3, be3,
                                            Wf1, bf1, Wf2, bf2,
                                            (float*)d_out);
}

// Round 4
// 170.158 us; speedup vs baseline: 1.2944x; 1.0059x over previous
//
#include <hip/hip_runtime.h>
#include <hip/hip_bf16.h>

#define LN_EPS 1e-5f

typedef __attribute__((ext_vector_type(8))) short bf16x8;
typedef __attribute__((ext_vector_type(4))) float f32x4;

// ---- LDS arena (ushort units). Row stride S=136 (272 B, 16B-aligned,
// bank offset 68 dw == 4 mod 32 -> only free 2-way conflicts). ----
#define S 136
#define OFF_F  0      // feat -> T1t -> h1        (100 rows; spill reads into A)
#define OFF_A  13600  // W1p (112 rows) -> agg A  (rows 100-111 stay zero)
#define OFF_S  28832  // W2p (32 rows, 20-31 zero)
#define OFF_T2 33184  // T2t (32 rows, 20-31 zero)
#define FLT    37536  // float scratch
#define ARENA_U 37656

// float-region indices
#define FHG 0
#define FZ2 20
#define FZ3 40

// ---- ws layout (ushort units) ----
#define WS_W1P 0       // 112 x 128 bf16
#define WS_W2P 14336   // 32 x 128 bf16
#define WS_M2  18432   // 20 x 200 f32 (as 8000 ushorts)
#define WS_M3  26432   // 20 x 100 f32 (as 4000 ushorts)

__device__ __forceinline__ unsigned short bf16rne(float x) {
    union { float f; unsigned u; } v; v.f = x;
    unsigned r = (v.u + 0x7FFFu + ((v.u >> 16) & 1u)) >> 16;
    return (unsigned short)r;
}

__device__ __forceinline__ unsigned pk2(float a, float b) {
    __hip_bfloat162 h = __float22bfloat162_rn(float2{a, b});
    unsigned r; __builtin_memcpy(&r, &h, 4); return r;
}

__device__ __forceinline__ void st4bf(unsigned short* p, const f32x4 v) {
    *(uint2*)p = make_uint2(pk2(v[0], v[1]), pk2(v[2], v[3]));
}

// K=128 pass, NT n-tiles, two m-tile rows (mr1<0 -> single).
// A row-major [m][k] at Abase; B as Bt[n][k] at Bbase. k-pads are zero.
template<int NT>
__device__ __forceinline__ void gemm_tiles(const unsigned short* __restrict__ ar,
    int Abase, int Bbase, int mr0, int mr1, int lm, int lq,
    f32x4 (&acc0)[NT], f32x4 (&acc1)[NT])
{
    #pragma unroll
    for (int ks = 0; ks < 4; ++ks) {
        const int k = ks * 32 + lq * 8;
        bf16x8 a0 = *(const bf16x8*)&ar[Abase + (mr0 * 16 + lm) * S + k];
        bf16x8 a1 = a0;
        if (mr1 >= 0) a1 = *(const bf16x8*)&ar[Abase + (mr1 * 16 + lm) * S + k];
        #pragma unroll
        for (int n = 0; n < NT; ++n) {
            bf16x8 b = *(const bf16x8*)&ar[Bbase + (n * 16 + lm) * S + k];
            acc0[n] = __builtin_amdgcn_mfma_f32_16x16x32_bf16(a0, b, acc0[n], 0, 0, 0);
            if (mr1 >= 0)
                acc1[n] = __builtin_amdgcn_mfma_f32_16x16x32_bf16(a1, b, acc1[n], 0, 0, 0);
        }
    }
}

// ---------------- prep: weights -> bf16 padded; fold Wo@Wv ----------------
__global__ __launch_bounds__(256) void prep_kernel(
    const float* __restrict__ W1, const float* __restrict__ W2,
    const float* __restrict__ Wv2, const float* __restrict__ Wo2,
    const float* __restrict__ Wv3, const float* __restrict__ Wo3,
    unsigned short* __restrict__ wsu)
{
    const int b = blockIdx.x, t = threadIdx.x;
    if (b < 4) {
        for (int i = t; i < 28 * 128; i += 256) {
            const int r = b * 28 + (i >> 7), k = i & 127;
            const float v = (r < 100 && k < 100) ? W1[r * 100 + k] : 0.f;
            wsu[WS_W1P + r * 128 + k] = bf16rne(v);
        }
    } else if (b == 4) {
        for (int i = t; i < 32 * 128; i += 256) {
            const int r = i >> 7, k = i & 127;
            const float v = (r < 20 && k < 100) ? W2[r * 100 + k] : 0.f;
            wsu[WS_W2P + i] = bf16rne(v);
        }
    } else if (b < 7) {
        float* M2 = (float*)(wsu + WS_M2);
        for (int i = t + (b - 5) * 2000; i < (b - 4) * 2000; i += 256) {
            const int j = i / 200, c = i % 200;
            float s = 0.f;
            #pragma unroll
            for (int q = 0; q < 32; ++q) s += Wo2[j * 32 + q] * Wv2[q * 200 + c];
            M2[i] = s;
        }
    } else {
        float* M3 = (float*)(wsu + WS_M3);
        for (int i = t; i < 2000; i += 256) {
            const int j = i / 100, c = i % 100;
            float s = 0.f;
            #pragma unroll
            for (int q = 0; q < 32; ++q) s += Wo3[j * 32 + q] * Wv3[q * 100 + c];
            M3[i] = s;
        }
    }
}

// ---------------- main fused kernel: one block per graph ----------------
__global__ __launch_bounds__(256) void fused_net_v4(
    const float* __restrict__ feat, const int* __restrict__ edge_src,
    const float* __restrict__ self_feat, const float* __restrict__ x3d,
    const unsigned short* __restrict__ wsu,
    const float* __restrict__ b1, const float* __restrict__ b2,
    const float* __restrict__ g2, const float* __restrict__ be2,
    const float* __restrict__ g3, const float* __restrict__ be3,
    const float* __restrict__ Wf1, const float* __restrict__ bf1,
    const float* __restrict__ Wf2, const float* __restrict__ bf2,
    float* __restrict__ out)
{
    __shared__ __align__(16) unsigned short ar[ARENA_U];
    float* fl = (float*)&ar[FLT];

    const int g    = blockIdx.x;
    const int tid  = threadIdx.x;
    const int w    = tid >> 6;
    const int lane = tid & 63;
    const int lm   = lane & 15;
    const int lq   = lane >> 4;
    const int mr0  = w;
    const int mr1  = (w + 4 < 7) ? (w + 4) : -1;

    int er[16];   // edge sources (local), threads 96..195 own row tid-96

    // ================= P0: stage everything =================
    {
        const float* fg = feat + g * 10000;
        for (int i = tid; i < 2500; i += 256) {
            const int n = i / 25, k4 = (i % 25) * 4;
            const float4 v = *(const float4*)&fg[n * 100 + k4];
            *(uint2*)&ar[OFF_F + n * S + k4] = make_uint2(pk2(v.x, v.y), pk2(v.z, v.w));
        }
        for (int i = tid; i < 700; i += 256) {             // feat k-pad zero
            const int n = i / 7, j = (i % 7) * 4;
            *(uint2*)&ar[OFF_F + n * S + 100 + j] = make_uint2(0u, 0u);
        }
        const uint4 z4i = make_uint4(0u, 0u, 0u, 0u);
        for (int i = tid; i < 1792; i += 256) {            // W1p copy (bf16)
            const int r = i >> 4, p = (i & 15) * 8;
            *(uint4*)&ar[OFF_A + r * S + p] = *(const uint4*)&wsu[WS_W1P + r * 128 + p];
        }
        for (int i = tid; i < 512; i += 256) {             // W2p copy
            const int r = i >> 4, p = (i & 15) * 8;
            *(uint4*)&ar[OFF_S + r * S + p] = *(const uint4*)&wsu[WS_W2P + r * 128 + p];
        }
        for (int i = tid; i < 544; i += 256) {             // T2t zero (32 rows)
            const int r = i / 17, p = (i % 17) * 8;
            *(uint4*)&ar[OFF_T2 + r * S + p] = z4i;
        }
        if (tid < 20) fl[FHG + tid] = 0.f;

        if (tid >= 96 && tid < 196) {                      // edge preload
            const int* ep = edge_src + g * 1600 + (tid - 96) * 16;
            int4 e;
            e = *(const int4*)&ep[0];  er[0]=e.x;  er[1]=e.y;  er[2]=e.z;  er[3]=e.w;
            e = *(const int4*)&ep[4];  er[4]=e.x;  er[5]=e.y;  er[6]=e.z;  er[7]=e.w;
            e = *(const int4*)&ep[8];  er[8]=e.x;  er[9]=e.y;  er[10]=e.z; er[11]=e.w;
            e = *(const int4*)&ep[12]; er[12]=e.x; er[13]=e.y; er[14]=e.z; er[15]=e.w;
            const int base = g * 100;
            #pragma unroll
            for (int i = 0; i < 16; ++i) er[i] -= base;
        } else if (tid >= 196 && tid < 216) {              // Z3 = M3 @ x3d_g
            const int j = tid - 196;
            const float* m3 = (const float*)(wsu + WS_M3) + j * 100;
            const float* xr = x3d + g * 100;
            float s = 0.f;
            for (int c = 0; c < 25; ++c) {
                const float4 a = *(const float4*)&m3[c * 4];
                const float4 x = *(const float4*)&xr[c * 4];
                s += a.x * x.x + a.y * x.y + a.z * x.z + a.w * x.w;
            }
            fl[FZ3 + j] = s;
        } else if (tid >= 216) {                           // Z2 = M2 @ sf_g (paired)
            const int q = tid - 216, j = q >> 1, h = (q & 1) * 100;
            const float* m2 = (const float*)(wsu + WS_M2) + j * 200 + h;
            const float* sr = self_feat + g * 200 + h;
            float s = 0.f;
            for (int c = 0; c < 25; ++c) {
                const float4 a = *(const float4*)&m2[c * 4];
                const float4 x = *(const float4*)&sr[c * 4];
                s += a.x * x.x + a.y * x.y + a.z * x.z + a.w * x.w;
            }
            s += __shfl_xor(s, 1);
            if (!(q & 1)) fl[FZ2 + j] = s;
        }
    }
    __syncthreads();

    // ================= P1: GEMM1  C = feat @ W1^T =================
    f32x4 acc0[7], acc1[7];
    {
        const f32x4 z = {0.f, 0.f, 0.f, 0.f};
        #pragma unroll
        for (int n = 0; n < 7; ++n) { acc0[n] = z; acc1[n] = z; }
    }
    gemm_tiles<7>(ar, OFF_F, OFF_A, mr0, mr1, lm, lq, acc0, acc1);
    __syncthreads();

    // ================= P2: write T1t into F; build A row-private =================
    {
        #pragma unroll
        for (int n = 0; n < 7; ++n) {
            const int cc = n * 16 + lm, m0 = mr0 * 16 + lq * 4;     // cc=f1, m0=node
            if (cc < 100 && m0 <= 96) st4bf(&ar[OFF_F + cc * S + m0], acc0[n]);
        }
        if (mr1 >= 0) {
            #pragma unroll
            for (int n = 0; n < 7; ++n) {
                const int cc = n * 16 + lm, m0 = mr1 * 16 + lq * 4;
                if (cc < 100 && m0 <= 96) st4bf(&ar[OFF_F + cc * S + m0], acc1[n]);
            }
        }
        if (tid >= 96 && tid < 196) {
            const int r = tid - 96;
            const uint4 z4i = make_uint4(0u, 0u, 0u, 0u);
            #pragma unroll
            for (int p = 0; p < 17; ++p) *(uint4*)&ar[OFF_A + r * S + p * 8] = z4i;
            #pragma unroll
            for (int i = 0; i < 16; ++i) {
                int cnt = 0;
                #pragma unroll
                for (int j = 0; j < 16; ++j) cnt += (er[j] == er[i]);
                ar[OFF_A + r * S + er[i]] = bf16rne((float)cnt * 0.0625f);
            }
        }
    }
    __syncthreads();

    // ================= P3: GEMM2  C2t[f1][dst] = T1t @ A(B-op) =================
    {
        const f32x4 z = {0.f, 0.f, 0.f, 0.f};
        #pragma unroll
        for (int n = 0; n < 7; ++n) { acc0[n] = z; acc1[n] = z; }
    }
    gemm_tiles<7>(ar, OFF_F, OFF_A, mr0, mr1, lm, lq, acc0, acc1);
    __syncthreads();

    // ================= P4: h1 = relu(C2 + b1), node-major vector writes =================
    {
        const int m0a = mr0 * 16 + lq * 4;
        float4 bb0 = (m0a <= 96) ? *(const float4*)&b1[m0a] : make_float4(0,0,0,0);
        #pragma unroll
        for (int n = 0; n < 7; ++n) {
            const int cc = n * 16 + lm;                      // cc = dst node
            if (cc < 100 && m0a <= 96) {
                f32x4 v = acc0[n];
                v[0] = fmaxf(v[0] + bb0.x, 0.f); v[1] = fmaxf(v[1] + bb0.y, 0.f);
                v[2] = fmaxf(v[2] + bb0.z, 0.f); v[3] = fmaxf(v[3] + bb0.w, 0.f);
                st4bf(&ar[OFF_F + cc * S + m0a], v);
            }
        }
        if (mr1 >= 0) {
            const int m0b = mr1 * 16 + lq * 4;
            float4 bb1 = (m0b <= 96) ? *(const float4*)&b1[m0b] : make_float4(0,0,0,0);
            #pragma unroll
            for (int n = 0; n < 7; ++n) {
                const int cc = n * 16 + lm;
                if (cc < 100 && m0b <= 96) {
                    f32x4 v = acc1[n];
                    v[0] = fmaxf(v[0] + bb1.x, 0.f); v[1] = fmaxf(v[1] + bb1.y, 0.f);
                    v[2] = fmaxf(v[2] + bb1.z, 0.f); v[3] = fmaxf(v[3] + bb1.w, 0.f);
                    st4bf(&ar[OFF_F + cc * S + m0b], v);
                }
            }
        }
    }
    __syncthreads();

    // ================= P5: GEMM3  T2t[f2][node] = W2p @ h1(B-op) =================
    {
        const int nt0 = w, nt1 = w + 4;
        const bool has1 = (nt1 < 7);
        const f32x4 z = {0.f, 0.f, 0.f, 0.f};
        f32x4 c00 = z, c10 = z, c01 = z, c11 = z;            // [mt][nt]
        #pragma unroll
        for (int ks = 0; ks < 4; ++ks) {
            const int k = ks * 32 + lq * 8;
            bf16x8 a0 = *(const bf16x8*)&ar[OFF_S + lm * S + k];
            bf16x8 a1 = *(const bf16x8*)&ar[OFF_S + (16 + lm) * S + k];
            bf16x8 b0 = *(const bf16x8*)&ar[OFF_F + (nt0 * 16 + lm) * S + k];
            c00 = __builtin_amdgcn_mfma_f32_16x16x32_bf16(a0, b0, c00, 0, 0, 0);
            c10 = __builtin_amdgcn_mfma_f32_16x16x32_bf16(a1, b0, c10, 0, 0, 0);
            if (has1) {
                bf16x8 b1v = *(const bf16x8*)&ar[OFF_F + (nt1 * 16 + lm) * S + k];
                c01 = __builtin_amdgcn_mfma_f32_16x16x32_bf16(a0, b1v, c01, 0, 0, 0);
                c11 = __builtin_amdgcn_mfma_f32_16x16x32_bf16(a1, b1v, c11, 0, 0, 0);
            }
        }
        // write T2t (scalar u16, ~2K elems total)
        {
            const int cc0 = nt0 * 16 + lm;
            if (cc0 < 100) {
                #pragma unroll
                for (int r = 0; r < 4; ++r) {
                    const int f2a = lq * 4 + r;
                    ar[OFF_T2 + f2a * S + cc0] = bf16rne(c00[r]);
                    const int f2b = 16 + lq * 4 + r;
                    if (f2b < 20) ar[OFF_T2 + f2b * S + cc0] = bf16rne(c10[r]);
                }
            }
            if (has1) {
                const int cc1 = nt1 * 16 + lm;
                if (cc1 < 100) {
                    #pragma unroll
                    for (int r = 0; r < 4; ++r) {
                        const int f2a = lq * 4 + r;
                        ar[OFF_T2 + f2a * S + cc1] = bf16rne(c01[r]);
                        const int f2b = 16 + lq * 4 + r;
                        if (f2b < 20) ar[OFF_T2 + f2b * S + cc1] = bf16rne(c11[r]);
                    }
                }
            }
        }
    }
    __syncthreads();

    // ================= P6: GEMM4  C4t[f2][dst] = T2t @ A(B-op); reduce =================
    {
        const int nt0 = w, nt1 = w + 4;
        const bool has1 = (nt1 < 7);
        const f32x4 z = {0.f, 0.f, 0.f, 0.f};
        f32x4 c00 = z, c10 = z, c01 = z, c11 = z;
        #pragma unroll
        for (int ks = 0; ks < 4; ++ks) {
            const int k = ks * 32 + lq * 8;
            bf16x8 a0 = *(const bf16x8*)&ar[OFF_T2 + lm * S + k];
            bf16x8 a1 = *(const bf16x8*)&ar[OFF_T2 + (16 + lm) * S + k];
            bf16x8 b0 = *(const bf16x8*)&ar[OFF_A + (nt0 * 16 + lm) * S + k];
            c00 = __builtin_amdgcn_mfma_f32_16x16x32_bf16(a0, b0, c00, 0, 0, 0);
            c10 = __builtin_amdgcn_mfma_f32_16x16x32_bf16(a1, b0, c10, 0, 0, 0);
            if (has1) {
                bf16x8 b1v = *(const bf16x8*)&ar[OFF_A + (nt1 * 16 + lm) * S + k];
                c01 = __builtin_amdgcn_mfma_f32_16x16x32_bf16(a0, b1v, c01, 0, 0, 0);
                c11 = __builtin_amdgcn_mfma_f32_16x16x32_bf16(a1, b1v, c11, 0, 0, 0);
            }
        }
        // relu(+b2), sum over dst cols -> FHG
        #pragma unroll
        for (int mt = 0; mt < 2; ++mt) {
            const f32x4 ca = mt ? c10 : c00;
            const f32x4 cb = mt ? c11 : c01;
            #pragma unroll
            for (int r = 0; r < 4; ++r) {
                const int f2 = mt * 16 + lq * 4 + r;
                const bool fv = (f2 < 20);
                const float bias = fv ? b2[f2] : 0.f;
                const int cc0 = nt0 * 16 + lm;
                float val = (fv && cc0 < 100) ? fmaxf(ca[r] + bias, 0.f) : 0.f;
                if (has1) {
                    const int cc1 = nt1 * 16 + lm;
                    if (fv && cc1 < 100) val += fmaxf(cb[r] + bias, 0.f);
                }
                val += __shfl_xor(val, 1);
                val += __shfl_xor(val, 2);
                val += __shfl_xor(val, 4);
                val += __shfl_xor(val, 8);
                if (lm == 0 && fv) atomicAdd(&fl[FHG + f2], val);
            }
        }
    }
    __syncthreads();

    // ================= P7: tail on wave 0 (shuffles, no barriers) =================
    if (tid < 64) {
        const int j = tid;
        float y = 0.f;
        if (j < 20) y = fl[FHG + j] * 0.01f + fl[FZ2 + j];
        float s = y;
        s += __shfl_xor(s, 1); s += __shfl_xor(s, 2); s += __shfl_xor(s, 4);
        s += __shfl_xor(s, 8); s += __shfl_xor(s, 16);
        float mu = s * 0.05f;
        float d = (j < 20) ? (y - mu) : 0.f;
        float v = d * d;
        v += __shfl_xor(v, 1); v += __shfl_xor(v, 2); v += __shfl_xor(v, 4);
        v += __shfl_xor(v, 8); v += __shfl_xor(v, 16);
        const float inv1 = 1.f / sqrtf(v * 0.05f + LN_EPS);
        float y2 = 0.f;
        if (j < 20) y2 = d * inv1 * g2[j] + be2[j] + fl[FZ3 + j];
        float s2 = y2;
        s2 += __shfl_xor(s2, 1); s2 += __shfl_xor(s2, 2); s2 += __shfl_xor(s2, 4);
        s2 += __shfl_xor(s2, 8); s2 += __shfl_xor(s2, 16);
        const float mu2 = s2 * 0.05f;
        float d2 = (j < 20) ? (y2 - mu2) : 0.f;
        float v2 = d2 * d2;
        v2 += __shfl_xor(v2, 1); v2 += __shfl_xor(v2, 2); v2 += __shfl_xor(v2, 4);
        v2 += __shfl_xor(v2, 8); v2 += __shfl_xor(v2, 16);
        const float inv2 = 1.f / sqrtf(v2 * 0.05f + LN_EPS);
        float y3 = 0.f;
        if (j < 20) y3 = d2 * inv2 * g3[j] + be3[j];

        // MLP: broadcast shuffles must run with ALL lanes active (reads from
        // inactive source lanes return 0 on CDNA ds_bpermute) -- R3 bug.
        float acc = 0.f;
        {
            const int js = (j < 10) ? j : 0;        // clamp: safe loads for all lanes
            const float* wr = Wf1 + js * 20;
            #pragma unroll
            for (int k = 0; k < 20; ++k) {
                const float yk = __shfl(y3, k);     // all 64 lanes participate
                acc += wr[k] * yk;
            }
            const float bias = bf1[js];
            const float w2v  = Wf2[js];
            acc = (j < 10) ? fmaxf(acc + bias, 0.f) * w2v : 0.f;
        }
        acc += __shfl_xor(acc, 1); acc += __shfl_xor(acc, 2);
        acc += __shfl_xor(acc, 4); acc += __shfl_xor(acc, 8);
        if (j == 0) out[g] = acc + bf2[0];
    }
}

extern "C" void kernel_launch(void* const* d_in, const int* in_sizes, int n_in,
                              void* d_out, int out_size, void* d_ws, size_t ws_size,
                              hipStream_t stream) {
    const float* feat      = (const float*)d_in[0];
    const int*   edge_src  = (const int*)  d_in[1];
    // d_in[2] = edge_dst (implicit: node n's edges at n*16..n*16+15)
    const float* self_feat = (const float*)d_in[3];
    const float* x3d       = (const float*)d_in[4];
    const float* W1  = (const float*)d_in[5];
    const float* b1  = (const float*)d_in[6];
    const float* W2  = (const float*)d_in[7];
    const float* b2  = (const float*)d_in[8];
    // d_in[9]=Wq2, d_in[10]=Wk2 unused (length-1 softmax == 1)
    const float* Wv2 = (const float*)d_in[11];
    const float* Wo2 = (const float*)d_in[12];
    const float* g2  = (const float*)d_in[13];
    const float* be2 = (const float*)d_in[14];
    // d_in[15]=Wq3, d_in[16]=Wk3 unused
    const float* Wv3 = (const float*)d_in[17];
    const float* Wo3 = (const float*)d_in[18];
    const float* g3  = (const float*)d_in[19];
    const float* be3 = (const float*)d_in[20];
    const float* Wf1 = (const float*)d_in[21];
    const float* bf1 = (const float*)d_in[22];
    const float* Wf2 = (const float*)d_in[23];
    const float* bf2 = (const float*)d_in[24];

    unsigned short* wsu = (unsigned short*)d_ws;   // needs ~60 KB of ws

    prep_kernel<<<8, 256, 0, stream>>>(W1, W2, Wv2, Wo2, Wv3, Wo3, wsu);
    fused_net_v4<<<512, 256, 0, stream>>>(feat, edge_src, self_feat, x3d, wsu,
                                          b1, b2, g2, be2, g3, be3,
                                          Wf1, bf1, Wf2, bf2,
                                          (float*)d_out);
}

// Round 5
// 129.528 us; speedup vs baseline: 1.7004x; 1.3137x over previous
//
#include <hip/hip_runtime.h>
#include <hip/hip_bf16.h>

#define LN_EPS 1e-5f

typedef __attribute__((ext_vector_type(8))) short bf16x8;
typedef __attribute__((ext_vector_type(4))) float f32x4;

// ---- LDS arena (ushort units). Row stride S=136 (272 B, 16B-aligned;
// bank offset 68 dw == 4 mod 32 -> only free 2-way conflicts). ----
#define S 136
#define OFF_F  0      // feat -> T1t -> h1        (100 rows; m/n spill reads land in A)
#define OFF_A  13600  // W1p (100 rows) -> agg A  (rows 100-111 read-only spill, discarded)
#define OFF_S  28832  // W2p (32 rows; 20-31 garbage -> discarded C rows)
#define OFF_T2 33184  // T2t (32 rows, zeroed; f2<20 written)
#define FLT    37536  // float scratch region (byte offset 75072, 16B aligned)
#define ARENA_U 39240 // 78480 B; x2 blocks = 156.9 KB <= 160 KB

// float-region indices (all multiples of 4)
#define FSF  0    // self_feat [200]
#define FX3  200  // x3d [100]
#define FB1  300  // b1 [100]
#define FB2  400  // b2 [20]
#define FG2  420
#define FBE2 440
#define FG3  460
#define FBE3 480
#define FWF1 500  // Wf1 [200]
#define FBF1 700  // bf1 [10] (+pad)
#define FWF2 712  // Wf2 [10] (+pad)
#define FBF2 724  // bf2 [1]  (+pad)
#define FV2  728  // V2 [32]
#define FV3  760  // V3 [32]
#define FZ2  792  // Z2 [20]
#define FZ3  812  // Z3 [20]
#define FHG  832  // hg accumulator [20]

__device__ __forceinline__ unsigned short bf16rne(float x) {
    union { float f; unsigned u; } v; v.f = x;
    unsigned r = (v.u + 0x7FFFu + ((v.u >> 16) & 1u)) >> 16;
    return (unsigned short)r;
}

__device__ __forceinline__ unsigned pk2(float a, float b) {
    __hip_bfloat162 h = __float22bfloat162_rn(float2{a, b});
    unsigned r; __builtin_memcpy(&r, &h, 4); return r;
}

__device__ __forceinline__ void st4bf(unsigned short* p, const f32x4 v) {
    *(uint2*)p = make_uint2(pk2(v[0], v[1]), pk2(v[2], v[3]));
}

// K=128 pass, one m-tile row, NT n-tiles. A row-major [m][k]; B as Bt[n][k].
template<int NT>
__device__ __forceinline__ void gemm_row(const unsigned short* __restrict__ ar,
    int Abase, int Bbase, int mrow, int lm, int lq, f32x4 (&acc)[NT])
{
    #pragma unroll
    for (int ks = 0; ks < 4; ++ks) {
        const int k = ks * 32 + lq * 8;
        bf16x8 a = *(const bf16x8*)&ar[Abase + (mrow * 16 + lm) * S + k];
        #pragma unroll
        for (int n = 0; n < NT; ++n) {
            bf16x8 b = *(const bf16x8*)&ar[Bbase + (n * 16 + lm) * S + k];
            acc[n] = __builtin_amdgcn_mfma_f32_16x16x32_bf16(a, b, acc[n], 0, 0, 0);
        }
    }
}

// One block per graph, 512 threads (8 waves): 4 waves/SIMD at 2 blocks/CU.
__global__ __launch_bounds__(512, 4) void fused_net_v5(
    const float* __restrict__ feat, const int* __restrict__ edge_src,
    const float* __restrict__ self_feat, const float* __restrict__ x3d,
    const float* __restrict__ W1, const float* __restrict__ b1,
    const float* __restrict__ W2, const float* __restrict__ b2,
    const float* __restrict__ Wv2, const float* __restrict__ Wo2,
    const float* __restrict__ g2, const float* __restrict__ be2,
    const float* __restrict__ Wv3, const float* __restrict__ Wo3,
    const float* __restrict__ g3, const float* __restrict__ be3,
    const float* __restrict__ Wf1, const float* __restrict__ bf1,
    const float* __restrict__ Wf2, const float* __restrict__ bf2,
    float* __restrict__ out)
{
    __shared__ __align__(16) unsigned short ar[ARENA_U];
    float* fl = (float*)&ar[FLT];

    const int g    = blockIdx.x;
    const int tid  = threadIdx.x;
    const int w    = tid >> 6;      // 0..7
    const int lane = tid & 63;
    const int lm   = lane & 15;
    const int lq   = lane >> 4;

    // A-build ownership: wave 7 -> rows 0..63, wave 6 lanes 0..35 -> rows 64..99
    int arow = -1;
    if (w == 7) arow = lane;
    else if (w == 6 && lane < 36) arow = 64 + lane;
    int er[16];

    // ================= P0: stage everything =================
    {
        // small per-graph / param vectors -> LDS float region
        if (tid < 50) *(float4*)&fl[FSF + tid * 4] = *(const float4*)&self_feat[g * 200 + tid * 4];
        else if (tid < 75)  *(float4*)&fl[FX3 + (tid - 50) * 4] = *(const float4*)&x3d[g * 100 + (tid - 50) * 4];
        else if (tid < 100) *(float4*)&fl[FB1 + (tid - 75) * 4] = *(const float4*)&b1[(tid - 75) * 4];
        else if (tid < 105) *(float4*)&fl[FB2 + (tid - 100) * 4] = *(const float4*)&b2[(tid - 100) * 4];
        else if (tid < 110) *(float4*)&fl[FG2 + (tid - 105) * 4] = *(const float4*)&g2[(tid - 105) * 4];
        else if (tid < 115) *(float4*)&fl[FBE2 + (tid - 110) * 4] = *(const float4*)&be2[(tid - 110) * 4];
        else if (tid < 120) *(float4*)&fl[FG3 + (tid - 115) * 4] = *(const float4*)&g3[(tid - 115) * 4];
        else if (tid < 125) *(float4*)&fl[FBE3 + (tid - 120) * 4] = *(const float4*)&be3[(tid - 120) * 4];
        else if (tid < 175) *(float4*)&fl[FWF1 + (tid - 125) * 4] = *(const float4*)&Wf1[(tid - 125) * 4];
        else if (tid < 185) { const int j = tid - 175; fl[FBF1 + j] = bf1[j]; fl[FWF2 + j] = Wf2[j]; }
        else if (tid == 185) fl[FBF2] = bf2[0];
        else if (tid >= 186 && tid < 206) fl[FHG + (tid - 186)] = 0.f;

        if (arow >= 0) {                                  // edge preload -> regs
            const int* ep = edge_src + g * 1600 + arow * 16;
            int4 e;
            e = *(const int4*)&ep[0];  er[0]=e.x;  er[1]=e.y;  er[2]=e.z;  er[3]=e.w;
            e = *(const int4*)&ep[4];  er[4]=e.x;  er[5]=e.y;  er[6]=e.z;  er[7]=e.w;
            e = *(const int4*)&ep[8];  er[8]=e.x;  er[9]=e.y;  er[10]=e.z; er[11]=e.w;
            e = *(const int4*)&ep[12]; er[12]=e.x; er[13]=e.y; er[14]=e.z; er[15]=e.w;
            const int base = g * 100;
            #pragma unroll
            for (int i = 0; i < 16; ++i) er[i] -= base;
        }

        // feat -> OFF_F bf16
        const float* fg = feat + g * 10000;
        for (int i = tid; i < 2500; i += 512) {
            const int n = i / 25, k4 = (i % 25) * 4;
            const float4 v = *(const float4*)&fg[n * 100 + k4];
            *(uint2*)&ar[OFF_F + n * S + k4] = make_uint2(pk2(v.x, v.y), pk2(v.z, v.w));
        }
        for (int i = tid; i < 700; i += 512) {            // feat k-pad zero
            const int n = i / 7, j = (i % 7) * 4;
            *(uint2*)&ar[OFF_F + n * S + 100 + j] = make_uint2(0u, 0u);
        }
        // W1 -> OFF_A bf16 (rows 0-99; rows 100-111 never affect kept outputs)
        for (int i = tid; i < 2500; i += 512) {
            const int n = i / 25, k4 = (i % 25) * 4;
            const float4 v = *(const float4*)&W1[n * 100 + k4];
            *(uint2*)&ar[OFF_A + n * S + k4] = make_uint2(pk2(v.x, v.y), pk2(v.z, v.w));
        }
        for (int i = tid; i < 700; i += 512) {            // W1 k-pad zero
            const int n = i / 7, j = (i % 7) * 4;
            *(uint2*)&ar[OFF_A + n * S + 100 + j] = make_uint2(0u, 0u);
        }
        // W2 -> OFF_S bf16 (rows 0-19)
        for (int i = tid; i < 500; i += 512) {
            const int n = i / 25, k4 = (i % 25) * 4;
            const float4 v = *(const float4*)&W2[n * 100 + k4];
            *(uint2*)&ar[OFF_S + n * S + k4] = make_uint2(pk2(v.x, v.y), pk2(v.z, v.w));
        }
        for (int i = tid; i < 140; i += 512) {            // W2 k-pad zero
            const int n = i / 7, j = (i % 7) * 4;
            *(uint2*)&ar[OFF_S + n * S + 100 + j] = make_uint2(0u, 0u);
        }
        const uint4 z4i = make_uint4(0u, 0u, 0u, 0u);
        for (int i = tid; i < 544; i += 512) {            // T2t zero (32 full rows)
            const int r = i / 17, p = (i % 17) * 8;
            *(uint4*)&ar[OFF_T2 + r * S + p] = z4i;
        }
    }
    __syncthreads();

    // ================= P1: GEMM1 C = feat @ W1^T (waves 0-6); V-dots (wave 7) ====
    f32x4 acc[7];
    {
        const f32x4 z = {0.f, 0.f, 0.f, 0.f};
        #pragma unroll
        for (int n = 0; n < 7; ++n) acc[n] = z;
    }
    if (w < 7) {
        gemm_row<7>(ar, OFF_F, OFF_A, w, lm, lq, acc);
    } else {
        const int j = lane >> 1, h = lane & 1;
        {   // V2[j] = Wv2[j] . self_feat   (pair-split over c)
            const float* wr = Wv2 + j * 200 + h * 100;
            float s = 0.f;
            for (int c = 0; c < 25; ++c) {
                const float4 a = *(const float4*)&wr[c * 4];
                const float4 x = *(const float4*)&fl[FSF + h * 100 + c * 4];
                s += a.x * x.x + a.y * x.y + a.z * x.z + a.w * x.w;
            }
            s += __shfl_xor(s, 1);
            if (h == 0) fl[FV2 + j] = s;
        }
        {   // V3[j] = Wv3[j] . x3d   (13/12 float4 split)
            const float* wr = Wv3 + j * 100;
            const int c0 = h ? 13 : 0, c1 = h ? 25 : 13;
            float s = 0.f;
            for (int c = c0; c < c1; ++c) {
                const float4 a = *(const float4*)&wr[c * 4];
                const float4 x = *(const float4*)&fl[FX3 + c * 4];
                s += a.x * x.x + a.y * x.y + a.z * x.z + a.w * x.w;
            }
            s += __shfl_xor(s, 1);
            if (h == 0) fl[FV3 + j] = s;
        }
    }
    __syncthreads();

    // ================= P2: T1t epilogue (waves 0-6) + A-build (waves 6,7) ========
    if (w < 7) {
        const int m0 = w * 16 + lq * 4;
        #pragma unroll
        for (int n = 0; n < 7; ++n) {
            const int cc = n * 16 + lm;                   // cc = f1, m0 = node
            if (cc < 100 && m0 <= 96) st4bf(&ar[OFF_F + cc * S + m0], acc[n]);
        }
    }
    if (arow >= 0) {
        const uint4 z4i = make_uint4(0u, 0u, 0u, 0u);
        #pragma unroll
        for (int p = 0; p < 17; ++p) *(uint4*)&ar[OFF_A + arow * S + p * 8] = z4i;
        #pragma unroll
        for (int i = 0; i < 16; ++i) {
            int cnt = 0;
            #pragma unroll
            for (int j = 0; j < 16; ++j) cnt += (er[j] == er[i]);
            ar[OFF_A + arow * S + er[i]] = bf16rne((float)cnt * 0.0625f);  // idempotent
        }
    }
    __syncthreads();

    // ================= P3: GEMM2 C2t[f1][dst] = T1t @ A (waves 0-6); Z (wave 7) ==
    {
        const f32x4 z = {0.f, 0.f, 0.f, 0.f};
        #pragma unroll
        for (int n = 0; n < 7; ++n) acc[n] = z;
    }
    if (w < 7) {
        gemm_row<7>(ar, OFF_F, OFF_A, w, lm, lq, acc);
    } else {
        if (lane < 20) {
            const float* wr = Wo2 + lane * 32;
            float s = 0.f;
            #pragma unroll
            for (int c = 0; c < 8; ++c) {
                const float4 a = *(const float4*)&wr[c * 4];
                s += a.x * fl[FV2 + c * 4] + a.y * fl[FV2 + c * 4 + 1]
                   + a.z * fl[FV2 + c * 4 + 2] + a.w * fl[FV2 + c * 4 + 3];
            }
            fl[FZ2 + lane] = s;
        } else if (lane < 40) {
            const int j = lane - 20;
            const float* wr = Wo3 + j * 32;
            float s = 0.f;
            #pragma unroll
            for (int c = 0; c < 8; ++c) {
                const float4 a = *(const float4*)&wr[c * 4];
                s += a.x * fl[FV3 + c * 4] + a.y * fl[FV3 + c * 4 + 1]
                   + a.z * fl[FV3 + c * 4 + 2] + a.w * fl[FV3 + c * 4 + 3];
            }
            fl[FZ3 + j] = s;
        }
    }
    __syncthreads();

    // ================= P4: h1 = relu(C2 + b1) node-major (waves 0-6) =============
    if (w < 7) {
        const int m0 = w * 16 + lq * 4;                   // m0 = f1 base
        if (m0 <= 96) {
            const float4 bb = *(const float4*)&fl[FB1 + m0];
            #pragma unroll
            for (int n = 0; n < 7; ++n) {
                const int cc = n * 16 + lm;               // cc = dst node
                if (cc < 100) {
                    f32x4 v = acc[n];
                    v[0] = fmaxf(v[0] + bb.x, 0.f); v[1] = fmaxf(v[1] + bb.y, 0.f);
                    v[2] = fmaxf(v[2] + bb.z, 0.f); v[3] = fmaxf(v[3] + bb.w, 0.f);
                    st4bf(&ar[OFF_F + cc * S + m0], v);
                }
            }
        }
    }
    __syncthreads();

    // ================= P5: GEMM3 T2t[f2][node] = W2p @ h1 (all 8 waves) ==========
    const int mt  = w & 1;
    const int ntA = w >> 1;            // 0..3
    const bool hasB = (w < 6);
    const int ntB = 4 + (w >> 1);      // 4..6
    {
        const f32x4 z = {0.f, 0.f, 0.f, 0.f};
        f32x4 cA = z, cB = z;
        #pragma unroll
        for (int ks = 0; ks < 4; ++ks) {
            const int k = ks * 32 + lq * 8;
            bf16x8 a = *(const bf16x8*)&ar[OFF_S + (mt * 16 + lm) * S + k];
            bf16x8 bA = *(const bf16x8*)&ar[OFF_F + (ntA * 16 + lm) * S + k];
            cA = __builtin_amdgcn_mfma_f32_16x16x32_bf16(a, bA, cA, 0, 0, 0);
            if (hasB) {
                bf16x8 bB = *(const bf16x8*)&ar[OFF_F + (ntB * 16 + lm) * S + k];
                cB = __builtin_amdgcn_mfma_f32_16x16x32_bf16(a, bB, cB, 0, 0, 0);
            }
        }
        const int ccA = ntA * 16 + lm;
        if (ccA < 100) {
            #pragma unroll
            for (int r = 0; r < 4; ++r) {
                const int f2 = mt * 16 + lq * 4 + r;
                if (f2 < 20) ar[OFF_T2 + f2 * S + ccA] = bf16rne(cA[r]);
            }
        }
        if (hasB) {
            const int ccB = ntB * 16 + lm;
            if (ccB < 100) {
                #pragma unroll
                for (int r = 0; r < 4; ++r) {
                    const int f2 = mt * 16 + lq * 4 + r;
                    if (f2 < 20) ar[OFF_T2 + f2 * S + ccB] = bf16rne(cB[r]);
                }
            }
        }
    }
    __syncthreads();

    // ================= P6: GEMM4 C4t[f2][dst] = T2t @ A; relu+b2 col-reduce ======
    {
        const f32x4 z = {0.f, 0.f, 0.f, 0.f};
        f32x4 cA = z, cB = z;
        #pragma unroll
        for (int ks = 0; ks < 4; ++ks) {
            const int k = ks * 32 + lq * 8;
            bf16x8 a = *(const bf16x8*)&ar[OFF_T2 + (mt * 16 + lm) * S + k];
            bf16x8 bA = *(const bf16x8*)&ar[OFF_A + (ntA * 16 + lm) * S + k];
            cA = __builtin_amdgcn_mfma_f32_16x16x32_bf16(a, bA, cA, 0, 0, 0);
            if (hasB) {
                bf16x8 bB = *(const bf16x8*)&ar[OFF_A + (ntB * 16 + lm) * S + k];
                cB = __builtin_amdgcn_mfma_f32_16x16x32_bf16(a, bB, cB, 0, 0, 0);
            }
        }
        const int ccA = ntA * 16 + lm;
        const int ccB = ntB * 16 + lm;
        #pragma unroll
        for (int r = 0; r < 4; ++r) {
            const int f2 = mt * 16 + lq * 4 + r;
            const bool fv = (f2 < 20);
            const float bias = fv ? fl[FB2 + (fv ? f2 : 0)] : 0.f;
            float val = (fv && ccA < 100) ? fmaxf(cA[r] + bias, 0.f) : 0.f;
            if (hasB && fv && ccB < 100) val += fmaxf(cB[r] + bias, 0.f);
            val += __shfl_xor(val, 1);
            val += __shfl_xor(val, 2);
            val += __shfl_xor(val, 4);
            val += __shfl_xor(val, 8);
            if (lm == 0 && fv) atomicAdd(&fl[FHG + f2], val);
        }
    }
    __syncthreads();

    // ================= P7: tail on wave 0 (all params in LDS) ====================
    if (tid < 64) {
        const int j = tid;
        float y = 0.f;
        if (j < 20) y = fl[FHG + j] * 0.01f + fl[FZ2 + j];
        float s = y;
        s += __shfl_xor(s, 1); s += __shfl_xor(s, 2); s += __shfl_xor(s, 4);
        s += __shfl_xor(s, 8); s += __shfl_xor(s, 16);
        const float mu = s * 0.05f;
        float d = (j < 20) ? (y - mu) : 0.f;
        float v = d * d;
        v += __shfl_xor(v, 1); v += __shfl_xor(v, 2); v += __shfl_xor(v, 4);
        v += __shfl_xor(v, 8); v += __shfl_xor(v, 16);
        const float inv1 = 1.f / sqrtf(v * 0.05f + LN_EPS);
        float y2 = 0.f;
        if (j < 20) y2 = d * inv1 * fl[FG2 + j] + fl[FBE2 + j] + fl[FZ3 + j];
        float s2 = y2;
        s2 += __shfl_xor(s2, 1); s2 += __shfl_xor(s2, 2); s2 += __shfl_xor(s2, 4);
        s2 += __shfl_xor(s2, 8); s2 += __shfl_xor(s2, 16);
        const float mu2 = s2 * 0.05f;
        float d2 = (j < 20) ? (y2 - mu2) : 0.f;
        float v2 = d2 * d2;
        v2 += __shfl_xor(v2, 1); v2 += __shfl_xor(v2, 2); v2 += __shfl_xor(v2, 4);
        v2 += __shfl_xor(v2, 8); v2 += __shfl_xor(v2, 16);
        const float inv2 = 1.f / sqrtf(v2 * 0.05f + LN_EPS);
        float y3 = 0.f;
        if (j < 20) y3 = d2 * inv2 * fl[FG3 + j] + fl[FBE3 + j];

        // MLP: broadcast shuffles with ALL 64 lanes active (CDNA reads from
        // inactive src lanes return 0 -- R3 lesson).
        float acc7 = 0.f;
        {
            const int js = (j < 10) ? j : 0;
            #pragma unroll
            for (int k = 0; k < 20; ++k) {
                const float yk = __shfl(y3, k);
                acc7 += fl[FWF1 + js * 20 + k] * yk;
            }
            const float bias = fl[FBF1 + js];
            const float w2v  = fl[FWF2 + js];
            acc7 = (j < 10) ? fmaxf(acc7 + bias, 0.f) * w2v : 0.f;
        }
        acc7 += __shfl_xor(acc7, 1); acc7 += __shfl_xor(acc7, 2);
        acc7 += __shfl_xor(acc7, 4); acc7 += __shfl_xor(acc7, 8);
        if (j == 0) out[g] = acc7 + fl[FBF2];
    }
}

extern "C" void kernel_launch(void* const* d_in, const int* in_sizes, int n_in,
                              void* d_out, int out_size, void* d_ws, size_t ws_size,
                              hipStream_t stream) {
    const float* feat      = (const float*)d_in[0];
    const int*   edge_src  = (const int*)  d_in[1];
    // d_in[2] = edge_dst (implicit: node n's edges at n*16..n*16+15)
    const float* self_feat = (const float*)d_in[3];
    const float* x3d       = (const float*)d_in[4];
    const float* W1  = (const float*)d_in[5];
    const float* b1  = (const float*)d_in[6];
    const float* W2  = (const float*)d_in[7];
    const float* b2  = (const float*)d_in[8];
    // d_in[9]=Wq2, d_in[10]=Wk2 unused (length-1 softmax == 1)
    const float* Wv2 = (const float*)d_in[11];
    const float* Wo2 = (const float*)d_in[12];
    const float* g2  = (const float*)d_in[13];
    const float* be2 = (const float*)d_in[14];
    // d_in[15]=Wq3, d_in[16]=Wk3 unused
    const float* Wv3 = (const float*)d_in[17];
    const float* Wo3 = (const float*)d_in[18];
    const float* g3  = (const float*)d_in[19];
    const float* be3 = (const float*)d_in[20];
    const float* Wf1 = (const float*)d_in[21];
    const float* bf1 = (const float*)d_in[22];
    const float* Wf2 = (const float*)d_in[23];
    const float* bf2 = (const float*)d_in[24];

    fused_net_v5<<<512, 512, 0, stream>>>(feat, edge_src, self_feat, x3d,
                                          W1, b1, W2, b2,
                                          Wv2, Wo2, g2, be2,
                                          Wv3, Wo3, g3, be3,
                                          Wf1, bf1, Wf2, bf2,
                                          (float*)d_out);
}